// Round 10
// baseline (526.357 us; speedup 1.0000x reference)
//
#include <hip/hip_runtime.h>
#include <hip/hip_cooperative_groups.h>
#include <stdint.h>

namespace cg = cooperative_groups;

#define TPB 256
#define NB  1024         // grid blocks (4/CU x 256 CU, cooperative-resident)
#define CHUNK 256        // elements per sampled chunk
#define NSAMP (NB * 4)   // sampled chunks (one per wave)

// d_ws float-index layout (~573 KB used; ws is much larger):
#define OFF_MM     256      // 2*NB  minmax partials {min,max}
#define OFF_ALLP   2560     // 512   all 128 candidate params (float4)
#define OFF_NMIN   3072     // 128
#define OFF_NMAX   3200     // 128
#define OFF_TOP    3328     // 32    top-8 params (float4)
#define OFF_TOPK   3360     // 8     top-8 ids (u32)
#define OFF_SCORES 3392     // 128   presel scores
#define OFF_PSC    4096     // 128*NB presel partials (candidate-major)
#define OFF_RPART  135168   // NB*8  rescore partials

// exact reference fp32 order — identical everywhere params are derived
__device__ __forceinline__ float4 cand_params(int k, float xmin, float xmax,
                                              float* nmin_out, float* nmax_out) {
    float xrange = xmax - xmin;
    int ii = k >> 4;
    float zpf = (float)(k & 15);
    float tmp_max = xrange / 8.0f * (float)(ii + 1);
    float tmp_delta = tmp_max / 15.0f;
    float shift = zpf * tmp_delta;
    float new_min = fmaxf(0.0f - shift, xmin);
    float new_max = fminf(tmp_max - shift, xmax);
    float min_neg = fminf(new_min, 0.0f);
    float max_pos = fmaxf(new_max, 0.0f);
    float scale = fmaxf((max_pos - min_neg) / 15.0f, 1e-8f);
    float zp = 0.0f - rintf(min_neg / scale);
    zp = fminf(fmaxf(zp, 0.0f), 15.0f);
    float4 p;
    p.x = 1.0f / scale;
    p.y = scale;
    p.z = 0.0f - zp;
    p.w = 15.0f - zp;
    *nmin_out = new_min;
    *nmax_out = new_max;
    return p;
}

#define QUANT1(xv) { \
    float t0_ = (xv) * p0.x; float r0_ = rintf(t0_); \
    float c0_ = __builtin_amdgcn_fmed3f(r0_, p0.z, p0.w); \
    float d0_ = __builtin_fmaf(c0_, p0.y, -(xv)); \
    a0 = __builtin_fmaf(d0_, d0_, a0); \
    float t1_ = (xv) * p1.x; float r1_ = rintf(t1_); \
    float c1_ = __builtin_amdgcn_fmed3f(r1_, p1.z, p1.w); \
    float d1_ = __builtin_fmaf(c1_, p1.y, -(xv)); \
    a1 = __builtin_fmaf(d1_, d1_, a1); }
#define QUANT4(V) { QUANT1(V.x) QUANT1(V.y) QUANT1(V.z) QUANT1(V.w) }

#define RQc(xv, qc, acc) { \
    float t_ = (xv) * qc.x; float r_ = rintf(t_); \
    float c_ = __builtin_amdgcn_fmed3f(r_, qc.z, qc.w); \
    float d_ = __builtin_fmaf(c_, qc.y, -(xv)); \
    acc = __builtin_fmaf(d_, d_, acc); }
#define RQ8(xv) { RQc(xv,q0,b0) RQc(xv,q1,b1) RQc(xv,q2,b2) RQc(xv,q3,b3) \
                  RQc(xv,q4,b4) RQc(xv,q5,b5) RQc(xv,q6,b6) RQc(xv,q7,b7) }

// ---------------- single cooperative kernel: all 6 phases ----------------
__global__ __launch_bounds__(TPB, 4) void k_all(const float* __restrict__ x, int n,
                                                float* __restrict__ W,
                                                float* __restrict__ out,
                                                int nwc, int gstride) {
    cg::grid_group gg = cg::this_grid();
    __shared__ float ls[4][CHUNK];       // 4 KB (P2 staging, wave-private)
    __shared__ float wsum[4][128];       // 2 KB (P2 / reused as [4][8] in P5)
    __shared__ float smn[4], smx[4];
    __shared__ float redP[TPB];
    __shared__ unsigned long long keys[128];
    __shared__ unsigned long long lmin[4];
    __shared__ int sel[8];
    __shared__ float red6[8][32];
    __shared__ float Sc6[8];

    int tid = threadIdx.x, lane = tid & 63;
    int wv = __builtin_amdgcn_readfirstlane(tid >> 6);
    int blk = blockIdx.x;
    long nl = (long)n;
    float* mm = W + OFF_MM;

    // ---- P1: minmax block partials ----
    {
        int n4 = n >> 2;
        const float4* x4 = (const float4*)x;
        float mn = INFINITY, mx = -INFINITY;
        int idx = blk * TPB + tid;
        int stride = NB * TPB;
        for (int i = idx; i < n4; i += stride) {
            float4 v = x4[i];
            mn = fminf(mn, fminf(fminf(v.x, v.y), fminf(v.z, v.w)));
            mx = fmaxf(mx, fmaxf(fmaxf(v.x, v.y), fmaxf(v.z, v.w)));
        }
        for (int i = (n4 << 2) + idx; i < n; i += stride) {
            float v = x[i];
            mn = fminf(mn, v);
            mx = fmaxf(mx, v);
        }
        #pragma unroll
        for (int m = 32; m; m >>= 1) {
            mn = fminf(mn, __shfl_xor(mn, m, 64));
            mx = fmaxf(mx, __shfl_xor(mx, m, 64));
        }
        if (lane == 0) { smn[wv] = mn; smx[wv] = mx; }
        __syncthreads();
        if (tid == 0) {
            mm[2 * blk + 0] = fminf(fminf(smn[0], smn[1]), fminf(smn[2], smn[3]));
            mm[2 * blk + 1] = fmaxf(fmaxf(smx[0], smx[1]), fmaxf(smx[2], smx[3]));
        }
    }
    gg.sync();

    // ---- P2: mm reduce, params, 1/8-sample presel ----
    {
        float mn = INFINITY, mx = -INFINITY;
        for (int e = tid; e < NB; e += TPB) {
            mn = fminf(mn, mm[2 * e + 0]);
            mx = fmaxf(mx, mm[2 * e + 1]);
        }
        #pragma unroll
        for (int m = 32; m; m >>= 1) {
            mn = fminf(mn, __shfl_xor(mn, m, 64));
            mx = fmaxf(mx, __shfl_xor(mx, m, 64));
        }
        if (lane == 0) { smn[wv] = mn; smx[wv] = mx; }
        __syncthreads();
        float xmin = fminf(fminf(smn[0], smn[1]), fminf(smn[2], smn[3]));
        float xmax = fmaxf(fmaxf(smx[0], smx[1]), fmaxf(smx[2], smx[3]));
        float nmi0, nma0, nmi1, nma1;
        float4 p0 = cand_params(2 * lane + 0, xmin, xmax, &nmi0, &nma0);
        float4 p1 = cand_params(2 * lane + 1, xmin, xmax, &nmi1, &nma1);
        if (blk == 0 && tid < 64) {
            ((float4*)(W + OFF_ALLP))[2 * lane + 0] = p0;
            ((float4*)(W + OFF_ALLP))[2 * lane + 1] = p1;
            W[OFF_NMIN + 2 * lane + 0] = nmi0;
            W[OFF_NMIN + 2 * lane + 1] = nmi1;
            W[OFF_NMAX + 2 * lane + 0] = nma0;
            W[OFF_NMAX + 2 * lane + 1] = nma1;
        }
        float a0 = 0.0f, a1 = 0.0f;
        long g = (long)(blk * 4 + wv) * gstride;   // deterministic sample
        if (g < (long)nwc) {
            long base = g * CHUNK;
            long e = base + (long)lane * 4;
            float4 v;
            if (base + CHUNK <= nl) {
                v = *(const float4*)(x + e);
            } else {
                v.x = (e + 0 < nl) ? x[e + 0] : 0.0f;   // pad scores 0 everywhere
                v.y = (e + 1 < nl) ? x[e + 1] : 0.0f;
                v.z = (e + 2 < nl) ? x[e + 2] : 0.0f;
                v.w = (e + 3 < nl) ? x[e + 3] : 0.0f;
            }
            *(float4*)(&ls[wv][lane * 4]) = v;
            asm volatile("s_waitcnt lgkmcnt(0)" ::: "memory");  // wave-private region
            __builtin_amdgcn_sched_barrier(0);
            const float4* l4 = (const float4*)(&ls[wv][0]);
            #pragma unroll 4
            for (int i = 0; i < CHUNK / 4; ++i) {
                float4 u = l4[i];
                QUANT4(u)
            }
        }
        wsum[wv][2 * lane + 0] = a0;
        wsum[wv][2 * lane + 1] = a1;
        __syncthreads();
        if (tid < 128) {
            W[OFF_PSC + (long)tid * NB + blk] =
                (wsum[0][tid] + wsum[1][tid]) + (wsum[2][tid] + wsum[3][tid]);
        }
    }
    gg.sync();

    // ---- P3: per-candidate score reduce (blocks 0..127, coalesced) ----
    if (blk < 128) {
        const float* p = W + OFF_PSC + (long)blk * NB;
        float s = 0.0f;
        for (int b = tid; b < NB; b += TPB) s += p[b];   // fixed per-thread order
        redP[tid] = s;
        __syncthreads();
        #pragma unroll
        for (int off = TPB / 2; off > 0; off >>= 1) {
            if (tid < off) redP[tid] += redP[tid + off]; // fixed tree
            __syncthreads();
        }
        if (tid == 0) W[OFF_SCORES + blk] = redP[0];
    }
    gg.sync();

    // ---- P4: top-8 lex-min selection (block 0) ----
    if (blk == 0) {
        if (tid < 128) {
            uint32_t tb = __float_as_uint(W[OFF_SCORES + tid]);
            tb = (tb & 0x80000000u) ? ~tb : (tb | 0x80000000u);  // order-preserving
            keys[tid] = (((unsigned long long)tb) << 32) | (unsigned)tid;
        }
        __syncthreads();
        for (int r = 0; r < 8; ++r) {
            unsigned long long kk = (tid < 128) ? keys[tid] : ~0ull;
            #pragma unroll
            for (int m = 32; m; m >>= 1) {
                unsigned long long o = __shfl_xor(kk, m, 64);
                kk = (o < kk) ? o : kk;
            }
            if ((tid & 63) == 0) lmin[wv] = kk;
            __syncthreads();
            if (tid == 0) {
                unsigned long long g2 = lmin[0];
                #pragma unroll
                for (int w = 1; w < 4; ++w) if (lmin[w] < g2) g2 = lmin[w];
                int kid = (int)(g2 & 0x7fu);
                sel[r] = kid;
                keys[kid] = ~0ull;
            }
            __syncthreads();
        }
        if (tid < 8) {
            ((float4*)(W + OFF_TOP))[tid] = ((const float4*)(W + OFF_ALLP))[sel[tid]];
            ((uint32_t*)(W + OFF_TOPK))[tid] = (uint32_t)sel[tid];
        }
    }
    gg.sync();

    // ---- P5: exact rescore of 8 finalists ----
    {
        const float4* P4v = (const float4*)(W + OFF_TOP);
        float4 q0 = P4v[0], q1 = P4v[1], q2 = P4v[2], q3 = P4v[3];
        float4 q4 = P4v[4], q5 = P4v[5], q6 = P4v[6], q7 = P4v[7];
        float b0 = 0, b1 = 0, b2 = 0, b3 = 0, b4 = 0, b5 = 0, b6 = 0, b7 = 0;
        int n4 = n >> 2;
        const float4* x4 = (const float4*)x;
        int gtid = blk * TPB + tid;
        int stride = NB * TPB;
        for (int i = gtid; i < n4; i += stride) {
            float4 v = x4[i];
            RQ8(v.x) RQ8(v.y) RQ8(v.z) RQ8(v.w)
        }
        for (int i = (n4 << 2) + gtid; i < n; i += stride) {
            float xv = x[i];
            RQ8(xv)
        }
        #pragma unroll
        for (int m = 32; m; m >>= 1) {
            b0 += __shfl_xor(b0, m, 64); b1 += __shfl_xor(b1, m, 64);
            b2 += __shfl_xor(b2, m, 64); b3 += __shfl_xor(b3, m, 64);
            b4 += __shfl_xor(b4, m, 64); b5 += __shfl_xor(b5, m, 64);
            b6 += __shfl_xor(b6, m, 64); b7 += __shfl_xor(b7, m, 64);
        }
        __syncthreads();   // wsum reuse: P2 readers done (post gg.sync, but keep tidy)
        if (lane == 0) {
            wsum[wv][0] = b0; wsum[wv][1] = b1; wsum[wv][2] = b2; wsum[wv][3] = b3;
            wsum[wv][4] = b4; wsum[wv][5] = b5; wsum[wv][6] = b6; wsum[wv][7] = b7;
        }
        __syncthreads();
        if (tid < 8) {
            W[OFF_RPART + (long)blk * 8 + tid] =
                (wsum[0][tid] + wsum[1][tid]) + (wsum[2][tid] + wsum[3][tid]);
        }
    }
    gg.sync();

    // ---- P6: final fixed-order reduce + lex (S,k) argmin (block 0) ----
    if (blk == 0) {
        int c = tid >> 5, j = tid & 31;
        float s = 0.0f;
        for (int b = j; b < NB; b += 32) s += W[OFF_RPART + (long)b * 8 + c];
        red6[c][j] = s;
        __syncthreads();
        if (j == 0) {
            float t = 0.0f;
            for (int jj = 0; jj < 32; ++jj) t += red6[c][jj];   // fixed order
            Sc6[c] = t;
        }
        __syncthreads();
        if (tid == 0) {
            const uint32_t* KK = (const uint32_t*)(W + OFF_TOPK);
            float bs = Sc6[0]; uint32_t bk = KK[0];
            for (int cc = 1; cc < 8; ++cc) {
                uint32_t kc = KK[cc];
                if (Sc6[cc] < bs || (Sc6[cc] == bs && kc < bk)) { bs = Sc6[cc]; bk = kc; }
            }
            out[0] = W[OFF_NMIN + bk];
            out[1] = W[OFF_NMAX + bk];
        }
    }
}

// ---------------- fallback path (R9 structure, same offsets) ----------------
__global__ __launch_bounds__(TPB) void k_minmax(const float* __restrict__ x, int n,
                                                float* __restrict__ mm) {
    int n4 = n >> 2;
    const float4* x4 = (const float4*)x;
    float mn = INFINITY, mx = -INFINITY;
    int idx = blockIdx.x * TPB + threadIdx.x;
    int stride = gridDim.x * TPB;
    for (int i = idx; i < n4; i += stride) {
        float4 v = x4[i];
        mn = fminf(mn, fminf(fminf(v.x, v.y), fminf(v.z, v.w)));
        mx = fmaxf(mx, fmaxf(fmaxf(v.x, v.y), fmaxf(v.z, v.w)));
    }
    for (int i = (n4 << 2) + idx; i < n; i += stride) {
        float v = x[i];
        mn = fminf(mn, v);
        mx = fmaxf(mx, v);
    }
    #pragma unroll
    for (int m = 32; m; m >>= 1) {
        mn = fminf(mn, __shfl_xor(mn, m, 64));
        mx = fmaxf(mx, __shfl_xor(mx, m, 64));
    }
    __shared__ float smn[4], smx[4];
    int wv = threadIdx.x >> 6;
    if ((threadIdx.x & 63) == 0) { smn[wv] = mn; smx[wv] = mx; }
    __syncthreads();
    if (threadIdx.x == 0) {
        mm[2 * blockIdx.x + 0] = fminf(fminf(smn[0], smn[1]), fminf(smn[2], smn[3]));
        mm[2 * blockIdx.x + 1] = fmaxf(fmaxf(smx[0], smx[1]), fmaxf(smx[2], smx[3]));
    }
}

__global__ __launch_bounds__(TPB) void k_presel(const float* __restrict__ x, int n,
                                                float* __restrict__ W, int nwc,
                                                int gstride) {
    __shared__ float ls[4][CHUNK];
    __shared__ float wsum[4][128];
    __shared__ float smn[4], smx[4];
    int tid = threadIdx.x, lane = tid & 63;
    int wv = __builtin_amdgcn_readfirstlane(threadIdx.x >> 6);
    const float* mm = W + OFF_MM;
    float mn = INFINITY, mx = -INFINITY;
    for (int e = tid; e < NB; e += TPB) {
        mn = fminf(mn, mm[2 * e + 0]);
        mx = fmaxf(mx, mm[2 * e + 1]);
    }
    #pragma unroll
    for (int m = 32; m; m >>= 1) {
        mn = fminf(mn, __shfl_xor(mn, m, 64));
        mx = fmaxf(mx, __shfl_xor(mx, m, 64));
    }
    if (lane == 0) { smn[wv] = mn; smx[wv] = mx; }
    __syncthreads();
    float xmin = fminf(fminf(smn[0], smn[1]), fminf(smn[2], smn[3]));
    float xmax = fmaxf(fmaxf(smx[0], smx[1]), fmaxf(smx[2], smx[3]));
    float nmi0, nma0, nmi1, nma1;
    float4 p0 = cand_params(2 * lane + 0, xmin, xmax, &nmi0, &nma0);
    float4 p1 = cand_params(2 * lane + 1, xmin, xmax, &nmi1, &nma1);
    if (blockIdx.x == 0 && tid < 64) {
        ((float4*)(W + OFF_ALLP))[2 * lane + 0] = p0;
        ((float4*)(W + OFF_ALLP))[2 * lane + 1] = p1;
        W[OFF_NMIN + 2 * lane + 0] = nmi0;
        W[OFF_NMIN + 2 * lane + 1] = nmi1;
        W[OFF_NMAX + 2 * lane + 0] = nma0;
        W[OFF_NMAX + 2 * lane + 1] = nma1;
    }
    float a0 = 0.0f, a1 = 0.0f;
    long nl = (long)n;
    long g = (long)(blockIdx.x * 4 + wv) * gstride;
    if (g < (long)nwc) {
        long base = g * CHUNK;
        long e = base + (long)lane * 4;
        float4 v;
        if (base + CHUNK <= nl) {
            v = *(const float4*)(x + e);
        } else {
            v.x = (e + 0 < nl) ? x[e + 0] : 0.0f;
            v.y = (e + 1 < nl) ? x[e + 1] : 0.0f;
            v.z = (e + 2 < nl) ? x[e + 2] : 0.0f;
            v.w = (e + 3 < nl) ? x[e + 3] : 0.0f;
        }
        *(float4*)(&ls[wv][lane * 4]) = v;
        asm volatile("s_waitcnt lgkmcnt(0)" ::: "memory");
        __builtin_amdgcn_sched_barrier(0);
        const float4* l4 = (const float4*)(&ls[wv][0]);
        #pragma unroll 4
        for (int i = 0; i < CHUNK / 4; ++i) {
            float4 u = l4[i];
            QUANT4(u)
        }
    }
    wsum[wv][2 * lane + 0] = a0;
    wsum[wv][2 * lane + 1] = a1;
    __syncthreads();
    if (tid < 128) {
        W[OFF_PSC + (long)tid * NB + blockIdx.x] =
            (wsum[0][tid] + wsum[1][tid]) + (wsum[2][tid] + wsum[3][tid]);
    }
}

__global__ void k_top(float* __restrict__ W) {
    __shared__ float red[128][8];
    __shared__ float sc[128];
    __shared__ unsigned long long keys[128];
    __shared__ unsigned long long lmin[16];
    __shared__ int sel[8];
    int t = threadIdx.x;
    int k = t >> 3, j = t & 7;
    const float* part = W + OFF_PSC;
    float s = 0.0f;
    for (int b = j; b < NB; b += 8) s += part[(long)k * NB + b];
    red[k][j] = s;
    __syncthreads();
    if (j == 0) {
        sc[k] = ((red[k][0] + red[k][1]) + (red[k][2] + red[k][3]))
              + ((red[k][4] + red[k][5]) + (red[k][6] + red[k][7]));
    }
    __syncthreads();
    if (t < 128) {
        uint32_t tb = __float_as_uint(sc[t]);
        tb = (tb & 0x80000000u) ? ~tb : (tb | 0x80000000u);
        keys[t] = (((unsigned long long)tb) << 32) | (unsigned)t;
    }
    __syncthreads();
    int wv = t >> 6;
    for (int r = 0; r < 8; ++r) {
        unsigned long long kk = (t < 128) ? keys[t] : ~0ull;
        #pragma unroll
        for (int m = 32; m; m >>= 1) {
            unsigned long long o = __shfl_xor(kk, m, 64);
            kk = (o < kk) ? o : kk;
        }
        if ((t & 63) == 0) lmin[wv] = kk;
        __syncthreads();
        if (t == 0) {
            unsigned long long g = lmin[0];
            for (int w = 1; w < 16; ++w) if (lmin[w] < g) g = lmin[w];
            int kid = (int)(g & 0x7fu);
            sel[r] = kid;
            keys[kid] = ~0ull;
        }
        __syncthreads();
    }
    if (t < 8) {
        ((float4*)(W + OFF_TOP))[t] = ((const float4*)(W + OFF_ALLP))[sel[t]];
        ((uint32_t*)(W + OFF_TOPK))[t] = (uint32_t)sel[t];
    }
}

__global__ __launch_bounds__(TPB) void k_rescore(const float* __restrict__ x, int n,
                                                 const float* __restrict__ W,
                                                 float* __restrict__ part) {
    const float4* P4v = (const float4*)(W + OFF_TOP);
    float4 q0 = P4v[0], q1 = P4v[1], q2 = P4v[2], q3 = P4v[3];
    float4 q4 = P4v[4], q5 = P4v[5], q6 = P4v[6], q7 = P4v[7];
    float b0 = 0, b1 = 0, b2 = 0, b3 = 0, b4 = 0, b5 = 0, b6 = 0, b7 = 0;
    int n4 = n >> 2;
    const float4* x4 = (const float4*)x;
    int gtid = blockIdx.x * TPB + threadIdx.x;
    int stride = gridDim.x * TPB;
    for (int i = gtid; i < n4; i += stride) {
        float4 v = x4[i];
        RQ8(v.x) RQ8(v.y) RQ8(v.z) RQ8(v.w)
    }
    for (int i = (n4 << 2) + gtid; i < n; i += stride) {
        float xv = x[i];
        RQ8(xv)
    }
    #pragma unroll
    for (int m = 32; m; m >>= 1) {
        b0 += __shfl_xor(b0, m, 64); b1 += __shfl_xor(b1, m, 64);
        b2 += __shfl_xor(b2, m, 64); b3 += __shfl_xor(b3, m, 64);
        b4 += __shfl_xor(b4, m, 64); b5 += __shfl_xor(b5, m, 64);
        b6 += __shfl_xor(b6, m, 64); b7 += __shfl_xor(b7, m, 64);
    }
    __shared__ float ws2[4][8];
    int wv = threadIdx.x >> 6;
    if ((threadIdx.x & 63) == 0) {
        ws2[wv][0] = b0; ws2[wv][1] = b1; ws2[wv][2] = b2; ws2[wv][3] = b3;
        ws2[wv][4] = b4; ws2[wv][5] = b5; ws2[wv][6] = b6; ws2[wv][7] = b7;
    }
    __syncthreads();
    if (threadIdx.x < 8) {
        part[(long)blockIdx.x * 8 + threadIdx.x] =
            (ws2[0][threadIdx.x] + ws2[1][threadIdx.x]) +
            (ws2[2][threadIdx.x] + ws2[3][threadIdx.x]);
    }
}

__global__ void k_fin(const float* __restrict__ part, const float* __restrict__ W,
                      float* __restrict__ out) {
    __shared__ float red[8][32];
    __shared__ float Sc[8];
    int tid = threadIdx.x;
    int c = tid >> 5, j = tid & 31;
    float s = 0.0f;
    for (int b = j; b < NB; b += 32) s += part[(long)b * 8 + c];
    red[c][j] = s;
    __syncthreads();
    if (j == 0) {
        float t = 0.0f;
        for (int jj = 0; jj < 32; ++jj) t += red[c][jj];
        Sc[c] = t;
    }
    __syncthreads();
    if (tid == 0) {
        const uint32_t* KK = (const uint32_t*)(W + OFF_TOPK);
        float bs = Sc[0]; uint32_t bk = KK[0];
        for (int cc = 1; cc < 8; ++cc) {
            uint32_t kc = KK[cc];
            if (Sc[cc] < bs || (Sc[cc] == bs && kc < bk)) { bs = Sc[cc]; bk = kc; }
        }
        out[0] = W[OFF_NMIN + bk];
        out[1] = W[OFF_NMAX + bk];
    }
}

extern "C" void kernel_launch(void* const* d_in, const int* in_sizes, int n_in,
                              void* d_out, int out_size, void* d_ws, size_t ws_size,
                              hipStream_t stream) {
    const float* x = (const float*)d_in[0];
    int n = in_sizes[0];
    float* out = (float*)d_out;
    float* W = (float*)d_ws;

    int nwc = (n + CHUNK - 1) / CHUNK;
    int gstride = nwc / NSAMP;
    if (gstride < 1) gstride = 1;

    void* args[] = { (void*)&x, (void*)&n, (void*)&W, (void*)&out,
                     (void*)&nwc, (void*)&gstride };
    hipError_t e = hipLaunchCooperativeKernel((const void*)k_all, dim3(NB), dim3(TPB),
                                              args, 0, stream);
    if (e != hipSuccess) {
        (void)hipGetLastError();   // clear sticky error, fall back to 5-kernel path
        k_minmax<<<NB, TPB, 0, stream>>>(x, n, W + OFF_MM);
        k_presel<<<NB, TPB, 0, stream>>>(x, n, W, nwc, gstride);
        k_top<<<1, 1024, 0, stream>>>(W);
        k_rescore<<<NB, TPB, 0, stream>>>(x, n, W, W + OFF_RPART);
        k_fin<<<1, TPB, 0, stream>>>(W + OFF_RPART, W, out);
    }
}

// Round 11
// 190.560 us; speedup vs baseline: 2.7622x; 2.7622x over previous
//
#include <hip/hip_runtime.h>
#include <stdint.h>

#define TPB 256
#define MMB 1024        // minmax grid blocks / mm partial pairs
#define PB  512         // presel grid blocks (2048 waves -> 1/16 sample, as proven in R9)
#define RB  1024        // rescore grid blocks
#define CHUNK 256       // elements per sampled chunk
#define NSAMP (PB * 4)  // sampled chunks (one per wave)

// d_ws float-index layout (~311 KB used):
#define OFF_CNT    0        // [0]=presel done-counter, [1]=rescore done-counter (u32)
#define OFF_MM     256      // 2*MMB minmax partials {min,max}
#define OFF_TOP    2304     // 8 * float4 top-8 params {inv_s, s, lo, hi}
#define OFF_TOPK   2336     // 8 u32 top-8 candidate ids
#define OFF_NMIN8  2352     // 8 new_min of top-8
#define OFF_NMAX8  2368     // 8 new_max of top-8
#define OFF_PSC    4096     // PB*128 presel partials, block-major [b][k]
#define OFF_RPART  69632    // RB*8 rescore partials

// exact reference fp32 order — identical everywhere params are derived
__device__ __forceinline__ float4 cand_params(int k, float xmin, float xmax,
                                              float* nmin_out, float* nmax_out) {
    float xrange = xmax - xmin;
    int ii = k >> 4;
    float zpf = (float)(k & 15);
    float tmp_max = xrange / 8.0f * (float)(ii + 1);
    float tmp_delta = tmp_max / 15.0f;
    float shift = zpf * tmp_delta;
    float new_min = fmaxf(0.0f - shift, xmin);
    float new_max = fminf(tmp_max - shift, xmax);
    float min_neg = fminf(new_min, 0.0f);
    float max_pos = fmaxf(new_max, 0.0f);
    float scale = fmaxf((max_pos - min_neg) / 15.0f, 1e-8f);
    float zp = 0.0f - rintf(min_neg / scale);
    zp = fminf(fmaxf(zp, 0.0f), 15.0f);
    float4 p;
    p.x = 1.0f / scale;
    p.y = scale;
    p.z = 0.0f - zp;
    p.w = 15.0f - zp;
    *nmin_out = new_min;
    *nmax_out = new_max;
    return p;
}

#define QUANT1(xv) { \
    float t0_ = (xv) * p0.x; float r0_ = rintf(t0_); \
    float c0_ = __builtin_amdgcn_fmed3f(r0_, p0.z, p0.w); \
    float d0_ = __builtin_fmaf(c0_, p0.y, -(xv)); \
    a0 = __builtin_fmaf(d0_, d0_, a0); \
    float t1_ = (xv) * p1.x; float r1_ = rintf(t1_); \
    float c1_ = __builtin_amdgcn_fmed3f(r1_, p1.z, p1.w); \
    float d1_ = __builtin_fmaf(c1_, p1.y, -(xv)); \
    a1 = __builtin_fmaf(d1_, d1_, a1); }
#define QUANT4(V) { QUANT1(V.x) QUANT1(V.y) QUANT1(V.z) QUANT1(V.w) }

#define RQc(xv, qc, acc) { \
    float t_ = (xv) * qc.x; float r_ = rintf(t_); \
    float c_ = __builtin_amdgcn_fmed3f(r_, qc.z, qc.w); \
    float d_ = __builtin_fmaf(c_, qc.y, -(xv)); \
    acc = __builtin_fmaf(d_, d_, acc); }
#define RQ8(xv) { RQc(xv,q0,b0) RQc(xv,q1,b1) RQc(xv,q2,b2) RQc(xv,q3,b3) \
                  RQc(xv,q4,b4) RQc(xv,q5,b5) RQc(xv,q6,b6) RQc(xv,q7,b7) }

#define ALOADF(p) __hip_atomic_load((p), __ATOMIC_RELAXED, __HIP_MEMORY_SCOPE_AGENT)

// ---- kernel 1: minmax block partials (+ zero the done-counters for this call) ----
__global__ __launch_bounds__(TPB) void k_minmax(const float* __restrict__ x, int n,
                                                float* __restrict__ W) {
    if (blockIdx.x == 0 && threadIdx.x < 2) {
        __hip_atomic_store(&((uint32_t*)W)[OFF_CNT + threadIdx.x], 0u,
                           __ATOMIC_RELAXED, __HIP_MEMORY_SCOPE_AGENT);
    }
    float* mm = W + OFF_MM;
    int n4 = n >> 2;
    const float4* x4 = (const float4*)x;
    float mn = INFINITY, mx = -INFINITY;
    int idx = blockIdx.x * TPB + threadIdx.x;
    int stride = gridDim.x * TPB;
    for (int i = idx; i < n4; i += stride) {
        float4 v = x4[i];
        mn = fminf(mn, fminf(fminf(v.x, v.y), fminf(v.z, v.w)));
        mx = fmaxf(mx, fmaxf(fmaxf(v.x, v.y), fmaxf(v.z, v.w)));
    }
    for (int i = (n4 << 2) + idx; i < n; i += stride) {
        float v = x[i];
        mn = fminf(mn, v);
        mx = fmaxf(mx, v);
    }
    #pragma unroll
    for (int m = 32; m; m >>= 1) {
        mn = fminf(mn, __shfl_xor(mn, m, 64));
        mx = fmaxf(mx, __shfl_xor(mx, m, 64));
    }
    __shared__ float smn[4], smx[4];
    int wv = threadIdx.x >> 6;
    if ((threadIdx.x & 63) == 0) { smn[wv] = mn; smx[wv] = mx; }
    __syncthreads();
    if (threadIdx.x == 0) {
        mm[2 * blockIdx.x + 0] = fminf(fminf(smn[0], smn[1]), fminf(smn[2], smn[3]));
        mm[2 * blockIdx.x + 1] = fmaxf(fmaxf(smx[0], smx[1]), fmaxf(smx[2], smx[3]));
    }
}

// ---- kernel 2: presel sample-score; last-arriving block reduces + selects top-8 ----
__global__ __launch_bounds__(TPB) void k_presel(const float* __restrict__ x, int n,
                                                float* __restrict__ W, int nwc,
                                                int gstride) {
    __shared__ float ls[4][CHUNK];
    __shared__ float wsum[4][128];
    __shared__ float smn[4], smx[4];
    __shared__ unsigned long long keys[128];
    __shared__ unsigned long long lmin[2];
    __shared__ int sel[8];
    __shared__ int lastFlag;
    int tid = threadIdx.x, lane = tid & 63;
    int wv = __builtin_amdgcn_readfirstlane(tid >> 6);
    const float* mm = W + OFF_MM;

    // exact global minmax (order-free fmin/fmax over partials)
    float mn = INFINITY, mx = -INFINITY;
    for (int e = tid; e < MMB; e += TPB) {
        mn = fminf(mn, mm[2 * e + 0]);
        mx = fmaxf(mx, mm[2 * e + 1]);
    }
    #pragma unroll
    for (int m = 32; m; m >>= 1) {
        mn = fminf(mn, __shfl_xor(mn, m, 64));
        mx = fmaxf(mx, __shfl_xor(mx, m, 64));
    }
    if (lane == 0) { smn[wv] = mn; smx[wv] = mx; }
    __syncthreads();
    float xmin = fminf(fminf(smn[0], smn[1]), fminf(smn[2], smn[3]));
    float xmax = fmaxf(fmaxf(smx[0], smx[1]), fmaxf(smx[2], smx[3]));
    float dum0, dum1;
    float4 p0 = cand_params(2 * lane + 0, xmin, xmax, &dum0, &dum1);
    float4 p1 = cand_params(2 * lane + 1, xmin, xmax, &dum0, &dum1);
    float a0 = 0.0f, a1 = 0.0f;
    long nl = (long)n;

    // deterministic 1/16 chunk sample, one chunk per wave (proven R9 body)
    long g = (long)(blockIdx.x * 4 + wv) * gstride;
    if (g < (long)nwc) {
        long base = g * CHUNK;
        long e = base + (long)lane * 4;
        float4 v;
        if (base + CHUNK <= nl) {
            v = *(const float4*)(x + e);
        } else {
            v.x = (e + 0 < nl) ? x[e + 0] : 0.0f;   // pad scores 0 for every cand
            v.y = (e + 1 < nl) ? x[e + 1] : 0.0f;
            v.z = (e + 2 < nl) ? x[e + 2] : 0.0f;
            v.w = (e + 3 < nl) ? x[e + 3] : 0.0f;
        }
        *(float4*)(&ls[wv][lane * 4]) = v;
        asm volatile("s_waitcnt lgkmcnt(0)" ::: "memory");  // wave-private region
        __builtin_amdgcn_sched_barrier(0);
        const float4* l4 = (const float4*)(&ls[wv][0]);
        #pragma unroll 4
        for (int i = 0; i < CHUNK / 4; ++i) {
            float4 u = l4[i];
            QUANT4(u)
        }
    }
    wsum[wv][2 * lane + 0] = a0;
    wsum[wv][2 * lane + 1] = a1;
    __syncthreads();
    if (tid < 128) {
        W[OFF_PSC + blockIdx.x * 128 + tid] =        // block-major, coalesced
            (wsum[0][tid] + wsum[1][tid]) + (wsum[2][tid] + wsum[3][tid]);
    }

    // completion detection (CUDA-guide threadfence pattern; no ordering assumption)
    __threadfence();
    __syncthreads();
    if (tid == 0) {
        uint32_t old = __hip_atomic_fetch_add(&((uint32_t*)W)[OFF_CNT + 0], 1u,
                                              __ATOMIC_ACQ_REL, __HIP_MEMORY_SCOPE_AGENT);
        lastFlag = (old == PB - 1);
    }
    __syncthreads();
    if (!lastFlag) return;
    __threadfence();   // acquire: all other blocks' partials now visible

    // tail (deterministic regardless of which block runs it): fixed-order score
    // reduce, top-8 lex-min selection, publish params/ids/nmin/nmax.
    float sc = 0.0f;
    if (tid < 128) {
        const float* p = W + OFF_PSC;
        float s0 = 0, s1 = 0, s2 = 0, s3 = 0;
        for (int b = 0; b < PB / 4; ++b) {           // fixed order per slice
            s0 += ALOADF(&p[(b + 0 * (PB / 4)) * 128 + tid]);
            s1 += ALOADF(&p[(b + 1 * (PB / 4)) * 128 + tid]);
            s2 += ALOADF(&p[(b + 2 * (PB / 4)) * 128 + tid]);
            s3 += ALOADF(&p[(b + 3 * (PB / 4)) * 128 + tid]);
        }
        sc = (s0 + s1) + (s2 + s3);
        uint32_t tb = __float_as_uint(sc);
        tb = (tb & 0x80000000u) ? ~tb : (tb | 0x80000000u);   // order-preserving
        keys[tid] = (((unsigned long long)tb) << 32) | (unsigned)tid;
    }
    __syncthreads();
    for (int r = 0; r < 8; ++r) {
        unsigned long long kk = (tid < 128) ? keys[tid] : ~0ull;
        #pragma unroll
        for (int m = 32; m; m >>= 1) {
            unsigned long long o = __shfl_xor(kk, m, 64);
            kk = (o < kk) ? o : kk;
        }
        if (tid == 0 || tid == 64) lmin[tid >> 6] = kk;
        __syncthreads();
        if (tid == 0) {
            unsigned long long g2 = (lmin[0] < lmin[1]) ? lmin[0] : lmin[1];
            int kid = (int)(g2 & 0x7fu);
            sel[r] = kid;
            keys[kid] = ~0ull;
        }
        __syncthreads();
    }
    if (tid < 8) {
        int kid = sel[tid];
        float nmi, nma;
        float4 p = cand_params(kid, xmin, xmax, &nmi, &nma);
        ((float4*)(W + OFF_TOP))[tid] = p;
        ((uint32_t*)(W + OFF_TOPK))[tid] = (uint32_t)kid;
        W[OFF_NMIN8 + tid] = nmi;
        W[OFF_NMAX8 + tid] = nma;
    }
}

// ---- kernel 3: exact rescore of 8 finalists; last block reduces + outputs ----
__global__ __launch_bounds__(TPB) void k_rescore(const float* __restrict__ x, int n,
                                                 float* __restrict__ W,
                                                 float* __restrict__ out) {
    __shared__ float ws2[4][8];
    __shared__ float red[8][32];
    __shared__ float Sc[8];
    __shared__ int lastFlag;
    const float4* P4v = (const float4*)(W + OFF_TOP);
    float4 q0 = P4v[0], q1 = P4v[1], q2 = P4v[2], q3 = P4v[3];
    float4 q4 = P4v[4], q5 = P4v[5], q6 = P4v[6], q7 = P4v[7];
    float b0 = 0, b1 = 0, b2 = 0, b3 = 0, b4 = 0, b5 = 0, b6 = 0, b7 = 0;
    int n4 = n >> 2;
    const float4* x4 = (const float4*)x;
    int tid = threadIdx.x;
    int gtid = blockIdx.x * TPB + tid;
    int stride = gridDim.x * TPB;
    for (int i = gtid; i < n4; i += stride) {
        float4 v = x4[i];
        RQ8(v.x) RQ8(v.y) RQ8(v.z) RQ8(v.w)
    }
    for (int i = (n4 << 2) + gtid; i < n; i += stride) {
        float xv = x[i];
        RQ8(xv)
    }
    #pragma unroll
    for (int m = 32; m; m >>= 1) {
        b0 += __shfl_xor(b0, m, 64); b1 += __shfl_xor(b1, m, 64);
        b2 += __shfl_xor(b2, m, 64); b3 += __shfl_xor(b3, m, 64);
        b4 += __shfl_xor(b4, m, 64); b5 += __shfl_xor(b5, m, 64);
        b6 += __shfl_xor(b6, m, 64); b7 += __shfl_xor(b7, m, 64);
    }
    int wv = tid >> 6;
    if ((tid & 63) == 0) {
        ws2[wv][0] = b0; ws2[wv][1] = b1; ws2[wv][2] = b2; ws2[wv][3] = b3;
        ws2[wv][4] = b4; ws2[wv][5] = b5; ws2[wv][6] = b6; ws2[wv][7] = b7;
    }
    __syncthreads();
    if (tid < 8) {
        W[OFF_RPART + blockIdx.x * 8 + tid] =
            (ws2[0][tid] + ws2[1][tid]) + (ws2[2][tid] + ws2[3][tid]);
    }

    __threadfence();
    __syncthreads();
    if (tid == 0) {
        uint32_t old = __hip_atomic_fetch_add(&((uint32_t*)W)[OFF_CNT + 1], 1u,
                                              __ATOMIC_ACQ_REL, __HIP_MEMORY_SCOPE_AGENT);
        lastFlag = (old == RB - 1);
    }
    __syncthreads();
    if (!lastFlag) return;
    __threadfence();

    // tail: fixed-order reduce of RB x 8 partials + lex (S,k) argmin + output
    int c = tid >> 5, j = tid & 31;
    float s = 0.0f;
    for (int b = j; b < RB; b += 32) s += ALOADF(&W[OFF_RPART + b * 8 + c]);
    red[c][j] = s;
    __syncthreads();
    if (j == 0) {
        float t = 0.0f;
        for (int jj = 0; jj < 32; ++jj) t += red[c][jj];    // fixed order
        Sc[c] = t;
    }
    __syncthreads();
    if (tid == 0) {
        const uint32_t* KK = (const uint32_t*)(W + OFF_TOPK);
        float bs = Sc[0]; uint32_t bk = KK[0]; int br = 0;
        for (int cc = 1; cc < 8; ++cc) {
            uint32_t kc = KK[cc];
            if (Sc[cc] < bs || (Sc[cc] == bs && kc < bk)) { bs = Sc[cc]; bk = kc; br = cc; }
        }
        out[0] = W[OFF_NMIN8 + br];
        out[1] = W[OFF_NMAX8 + br];
    }
}

extern "C" void kernel_launch(void* const* d_in, const int* in_sizes, int n_in,
                              void* d_out, int out_size, void* d_ws, size_t ws_size,
                              hipStream_t stream) {
    const float* x = (const float*)d_in[0];
    int n = in_sizes[0];
    float* out = (float*)d_out;
    float* W = (float*)d_ws;

    int nwc = (n + CHUNK - 1) / CHUNK;
    int gstride = nwc / NSAMP;
    if (gstride < 1) gstride = 1;

    k_minmax<<<MMB, TPB, 0, stream>>>(x, n, W);
    k_presel<<<PB, TPB, 0, stream>>>(x, n, W, nwc, gstride);
    k_rescore<<<RB, TPB, 0, stream>>>(x, n, W, out);
}

// Round 12
// 60.929 us; speedup vs baseline: 8.6388x; 3.1275x over previous
//
#include <hip/hip_runtime.h>
#include <stdint.h>

#define TPB 256
#define MMB 1024        // minmax grid blocks / mm partial pairs
#define PB  512         // presel grid blocks (2048 waves -> 1/16 sample, proven R9/R11)
#define RB  1024        // rescore grid blocks
#define CHUNK 256       // elements per sampled chunk
#define NSAMP (PB * 4)  // sampled chunks (one per wave)

// d_ws float-index layout (~311 KB used):
#define OFF_CNT    0        // [0]=presel done-counter, [1]=rescore done-counter (u32)
#define OFF_MM     256      // 2*MMB minmax partials {min,max}
#define OFF_TOP    2304     // 8 * float4 top-8 params {inv_s, s, lo, hi}
#define OFF_TOPK   2336     // 8 u32 top-8 candidate ids
#define OFF_NMIN8  2352     // 8 new_min of top-8
#define OFF_NMAX8  2368     // 8 new_max of top-8
#define OFF_PSC    4096     // PB*128 presel partials, block-major [b][k]
#define OFF_RPART  69632    // RB*8 rescore partials

// exact reference fp32 order — identical everywhere params are derived
__device__ __forceinline__ float4 cand_params(int k, float xmin, float xmax,
                                              float* nmin_out, float* nmax_out) {
    float xrange = xmax - xmin;
    int ii = k >> 4;
    float zpf = (float)(k & 15);
    float tmp_max = xrange / 8.0f * (float)(ii + 1);
    float tmp_delta = tmp_max / 15.0f;
    float shift = zpf * tmp_delta;
    float new_min = fmaxf(0.0f - shift, xmin);
    float new_max = fminf(tmp_max - shift, xmax);
    float min_neg = fminf(new_min, 0.0f);
    float max_pos = fmaxf(new_max, 0.0f);
    float scale = fmaxf((max_pos - min_neg) / 15.0f, 1e-8f);
    float zp = 0.0f - rintf(min_neg / scale);
    zp = fminf(fmaxf(zp, 0.0f), 15.0f);
    float4 p;
    p.x = 1.0f / scale;
    p.y = scale;
    p.z = 0.0f - zp;
    p.w = 15.0f - zp;
    *nmin_out = new_min;
    *nmax_out = new_max;
    return p;
}

#define QUANT1(xv) { \
    float t0_ = (xv) * p0.x; float r0_ = rintf(t0_); \
    float c0_ = __builtin_amdgcn_fmed3f(r0_, p0.z, p0.w); \
    float d0_ = __builtin_fmaf(c0_, p0.y, -(xv)); \
    a0 = __builtin_fmaf(d0_, d0_, a0); \
    float t1_ = (xv) * p1.x; float r1_ = rintf(t1_); \
    float c1_ = __builtin_amdgcn_fmed3f(r1_, p1.z, p1.w); \
    float d1_ = __builtin_fmaf(c1_, p1.y, -(xv)); \
    a1 = __builtin_fmaf(d1_, d1_, a1); }
#define QUANT4(V) { QUANT1(V.x) QUANT1(V.y) QUANT1(V.z) QUANT1(V.w) }

#define RQc(xv, qc, acc) { \
    float t_ = (xv) * qc.x; float r_ = rintf(t_); \
    float c_ = __builtin_amdgcn_fmed3f(r_, qc.z, qc.w); \
    float d_ = __builtin_fmaf(c_, qc.y, -(xv)); \
    acc = __builtin_fmaf(d_, d_, acc); }
#define RQ8(xv) { RQc(xv,q0,b0) RQc(xv,q1,b1) RQc(xv,q2,b2) RQc(xv,q3,b3) \
                  RQc(xv,q4,b4) RQc(xv,q5,b5) RQc(xv,q6,b6) RQc(xv,q7,b7) }

// relaxed agent-scope atomics: sc-bit path to/from the coherence point, NO
// cache writeback/invalidate ops (the R11 killer).
#define ALOADF(p)    __hip_atomic_load((p), __ATOMIC_RELAXED, __HIP_MEMORY_SCOPE_AGENT)
#define ASTOREF(p,v) __hip_atomic_store((p), (v), __ATOMIC_RELAXED, __HIP_MEMORY_SCOPE_AGENT)

// ---- kernel 1: minmax block partials (+ zero the done-counters for this call) ----
__global__ __launch_bounds__(TPB) void k_minmax(const float* __restrict__ x, int n,
                                                float* __restrict__ W) {
    if (blockIdx.x == 0 && threadIdx.x < 2) {
        __hip_atomic_store(&((uint32_t*)W)[OFF_CNT + threadIdx.x], 0u,
                           __ATOMIC_RELAXED, __HIP_MEMORY_SCOPE_AGENT);
    }
    float* mm = W + OFF_MM;
    int n4 = n >> 2;
    const float4* x4 = (const float4*)x;
    float mn = INFINITY, mx = -INFINITY;
    int idx = blockIdx.x * TPB + threadIdx.x;
    int stride = gridDim.x * TPB;
    for (int i = idx; i < n4; i += stride) {
        float4 v = x4[i];
        mn = fminf(mn, fminf(fminf(v.x, v.y), fminf(v.z, v.w)));
        mx = fmaxf(mx, fmaxf(fmaxf(v.x, v.y), fmaxf(v.z, v.w)));
    }
    for (int i = (n4 << 2) + idx; i < n; i += stride) {
        float v = x[i];
        mn = fminf(mn, v);
        mx = fmaxf(mx, v);
    }
    #pragma unroll
    for (int m = 32; m; m >>= 1) {
        mn = fminf(mn, __shfl_xor(mn, m, 64));
        mx = fmaxf(mx, __shfl_xor(mx, m, 64));
    }
    __shared__ float smn[4], smx[4];
    int wv = threadIdx.x >> 6;
    if ((threadIdx.x & 63) == 0) { smn[wv] = mn; smx[wv] = mx; }
    __syncthreads();
    if (threadIdx.x == 0) {
        mm[2 * blockIdx.x + 0] = fminf(fminf(smn[0], smn[1]), fminf(smn[2], smn[3]));
        mm[2 * blockIdx.x + 1] = fmaxf(fmaxf(smx[0], smx[1]), fmaxf(smx[2], smx[3]));
    }
}

// ---- kernel 2: presel sample-score; last-arriving block reduces + selects top-8 ----
__global__ __launch_bounds__(TPB) void k_presel(const float* __restrict__ x, int n,
                                                float* __restrict__ W, int nwc,
                                                int gstride) {
    __shared__ float ls[4][CHUNK];
    __shared__ float wsum[4][128];
    __shared__ float smn[4], smx[4];
    __shared__ unsigned long long keys[128];
    __shared__ unsigned long long lmin[2];
    __shared__ int sel[8];
    __shared__ int lastFlag;
    int tid = threadIdx.x, lane = tid & 63;
    int wv = __builtin_amdgcn_readfirstlane(tid >> 6);
    const float* mm = W + OFF_MM;

    // exact global minmax (order-free fmin/fmax over partials)
    float mn = INFINITY, mx = -INFINITY;
    for (int e = tid; e < MMB; e += TPB) {
        mn = fminf(mn, mm[2 * e + 0]);
        mx = fmaxf(mx, mm[2 * e + 1]);
    }
    #pragma unroll
    for (int m = 32; m; m >>= 1) {
        mn = fminf(mn, __shfl_xor(mn, m, 64));
        mx = fmaxf(mx, __shfl_xor(mx, m, 64));
    }
    if (lane == 0) { smn[wv] = mn; smx[wv] = mx; }
    __syncthreads();
    float xmin = fminf(fminf(smn[0], smn[1]), fminf(smn[2], smn[3]));
    float xmax = fmaxf(fmaxf(smx[0], smx[1]), fmaxf(smx[2], smx[3]));
    float dum0, dum1;
    float4 p0 = cand_params(2 * lane + 0, xmin, xmax, &dum0, &dum1);
    float4 p1 = cand_params(2 * lane + 1, xmin, xmax, &dum0, &dum1);
    float a0 = 0.0f, a1 = 0.0f;
    long nl = (long)n;

    // deterministic 1/16 chunk sample, one chunk per wave (proven body)
    long g = (long)(blockIdx.x * 4 + wv) * gstride;
    if (g < (long)nwc) {
        long base = g * CHUNK;
        long e = base + (long)lane * 4;
        float4 v;
        if (base + CHUNK <= nl) {
            v = *(const float4*)(x + e);
        } else {
            v.x = (e + 0 < nl) ? x[e + 0] : 0.0f;   // pad scores 0 for every cand
            v.y = (e + 1 < nl) ? x[e + 1] : 0.0f;
            v.z = (e + 2 < nl) ? x[e + 2] : 0.0f;
            v.w = (e + 3 < nl) ? x[e + 3] : 0.0f;
        }
        *(float4*)(&ls[wv][lane * 4]) = v;
        asm volatile("s_waitcnt lgkmcnt(0)" ::: "memory");  // wave-private region
        __builtin_amdgcn_sched_barrier(0);
        const float4* l4 = (const float4*)(&ls[wv][0]);
        #pragma unroll 4
        for (int i = 0; i < CHUNK / 4; ++i) {
            float4 u = l4[i];
            QUANT4(u)
        }
    }
    wsum[wv][2 * lane + 0] = a0;
    wsum[wv][2 * lane + 1] = a1;
    __syncthreads();
    if (tid < 128) {
        ASTOREF(&W[OFF_PSC + blockIdx.x * 128 + tid],        // agent-visible store
                (wsum[0][tid] + wsum[1][tid]) + (wsum[2][tid] + wsum[3][tid]));
    }
    // __syncthreads drains every wave's vmcnt -> partials globally visible
    __syncthreads();
    if (tid == 0) {
        uint32_t old = __hip_atomic_fetch_add(&((uint32_t*)W)[OFF_CNT + 0], 1u,
                                              __ATOMIC_RELAXED, __HIP_MEMORY_SCOPE_AGENT);
        lastFlag = (old == PB - 1);
    }
    __syncthreads();
    if (!lastFlag) return;

    // tail (deterministic regardless of which block runs it): fixed-order score
    // reduce (agent-scope loads), top-8 lex-min selection, publish.
    if (tid < 128) {
        const float* p = W + OFF_PSC;
        float s0 = 0, s1 = 0, s2 = 0, s3 = 0;
        for (int b = 0; b < PB / 4; ++b) {           // fixed order per slice
            s0 += ALOADF(&p[(b + 0 * (PB / 4)) * 128 + tid]);
            s1 += ALOADF(&p[(b + 1 * (PB / 4)) * 128 + tid]);
            s2 += ALOADF(&p[(b + 2 * (PB / 4)) * 128 + tid]);
            s3 += ALOADF(&p[(b + 3 * (PB / 4)) * 128 + tid]);
        }
        float sc = (s0 + s1) + (s2 + s3);
        uint32_t tb = __float_as_uint(sc);
        tb = (tb & 0x80000000u) ? ~tb : (tb | 0x80000000u);   // order-preserving
        keys[tid] = (((unsigned long long)tb) << 32) | (unsigned)tid;
    }
    __syncthreads();
    for (int r = 0; r < 8; ++r) {
        unsigned long long kk = (tid < 128) ? keys[tid] : ~0ull;
        #pragma unroll
        for (int m = 32; m; m >>= 1) {
            unsigned long long o = __shfl_xor(kk, m, 64);
            kk = (o < kk) ? o : kk;
        }
        if (tid == 0 || tid == 64) lmin[tid >> 6] = kk;
        __syncthreads();
        if (tid == 0) {
            unsigned long long g2 = (lmin[0] < lmin[1]) ? lmin[0] : lmin[1];
            int kid = (int)(g2 & 0x7fu);
            sel[r] = kid;
            keys[kid] = ~0ull;
        }
        __syncthreads();
    }
    if (tid < 8) {
        int kid = sel[tid];
        float nmi, nma;
        float4 p = cand_params(kid, xmin, xmax, &nmi, &nma);
        ((float4*)(W + OFF_TOP))[tid] = p;            // next-kernel handoff:
        ((uint32_t*)(W + OFF_TOPK))[tid] = (uint32_t)kid;  // implicit dispatch fences
        W[OFF_NMIN8 + tid] = nmi;
        W[OFF_NMAX8 + tid] = nma;
    }
}

// ---- kernel 3: exact rescore of 8 finalists; last block reduces + outputs ----
__global__ __launch_bounds__(TPB) void k_rescore(const float* __restrict__ x, int n,
                                                 float* __restrict__ W,
                                                 float* __restrict__ out) {
    __shared__ float ws2[4][8];
    __shared__ float red[8][32];
    __shared__ float Sc[8];
    __shared__ int lastFlag;
    const float4* P4v = (const float4*)(W + OFF_TOP);
    float4 q0 = P4v[0], q1 = P4v[1], q2 = P4v[2], q3 = P4v[3];
    float4 q4 = P4v[4], q5 = P4v[5], q6 = P4v[6], q7 = P4v[7];
    float b0 = 0, b1 = 0, b2 = 0, b3 = 0, b4 = 0, b5 = 0, b6 = 0, b7 = 0;
    int n4 = n >> 2;
    const float4* x4 = (const float4*)x;
    int tid = threadIdx.x;
    int gtid = blockIdx.x * TPB + tid;
    int stride = gridDim.x * TPB;
    for (int i = gtid; i < n4; i += stride) {
        float4 v = x4[i];
        RQ8(v.x) RQ8(v.y) RQ8(v.z) RQ8(v.w)
    }
    for (int i = (n4 << 2) + gtid; i < n; i += stride) {
        float xv = x[i];
        RQ8(xv)
    }
    #pragma unroll
    for (int m = 32; m; m >>= 1) {
        b0 += __shfl_xor(b0, m, 64); b1 += __shfl_xor(b1, m, 64);
        b2 += __shfl_xor(b2, m, 64); b3 += __shfl_xor(b3, m, 64);
        b4 += __shfl_xor(b4, m, 64); b5 += __shfl_xor(b5, m, 64);
        b6 += __shfl_xor(b6, m, 64); b7 += __shfl_xor(b7, m, 64);
    }
    int wv = tid >> 6;
    if ((tid & 63) == 0) {
        ws2[wv][0] = b0; ws2[wv][1] = b1; ws2[wv][2] = b2; ws2[wv][3] = b3;
        ws2[wv][4] = b4; ws2[wv][5] = b5; ws2[wv][6] = b6; ws2[wv][7] = b7;
    }
    __syncthreads();
    if (tid < 8) {
        ASTOREF(&W[OFF_RPART + blockIdx.x * 8 + tid],
                (ws2[0][tid] + ws2[1][tid]) + (ws2[2][tid] + ws2[3][tid]));
    }
    __syncthreads();   // drains vmcnt of the agent stores
    if (tid == 0) {
        uint32_t old = __hip_atomic_fetch_add(&((uint32_t*)W)[OFF_CNT + 1], 1u,
                                              __ATOMIC_RELAXED, __HIP_MEMORY_SCOPE_AGENT);
        lastFlag = (old == RB - 1);
    }
    __syncthreads();
    if (!lastFlag) return;

    // tail: fixed-order reduce of RB x 8 partials + lex (S,k) argmin + output
    int c = tid >> 5, j = tid & 31;
    float s = 0.0f;
    for (int b = j; b < RB; b += 32) s += ALOADF(&W[OFF_RPART + b * 8 + c]);
    red[c][j] = s;
    __syncthreads();
    if (j == 0) {
        float t = 0.0f;
        for (int jj = 0; jj < 32; ++jj) t += red[c][jj];    // fixed order
        Sc[c] = t;
    }
    __syncthreads();
    if (tid == 0) {
        const uint32_t* KK = (const uint32_t*)(W + OFF_TOPK);
        float bs = Sc[0]; uint32_t bk = KK[0]; int br = 0;
        for (int cc = 1; cc < 8; ++cc) {
            uint32_t kc = KK[cc];
            if (Sc[cc] < bs || (Sc[cc] == bs && kc < bk)) { bs = Sc[cc]; bk = kc; br = cc; }
        }
        out[0] = W[OFF_NMIN8 + br];
        out[1] = W[OFF_NMAX8 + br];
    }
}

extern "C" void kernel_launch(void* const* d_in, const int* in_sizes, int n_in,
                              void* d_out, int out_size, void* d_ws, size_t ws_size,
                              hipStream_t stream) {
    const float* x = (const float*)d_in[0];
    int n = in_sizes[0];
    float* out = (float*)d_out;
    float* W = (float*)d_ws;

    int nwc = (n + CHUNK - 1) / CHUNK;
    int gstride = nwc / NSAMP;
    if (gstride < 1) gstride = 1;

    k_minmax<<<MMB, TPB, 0, stream>>>(x, n, W);
    k_presel<<<PB, TPB, 0, stream>>>(x, n, W, nwc, gstride);
    k_rescore<<<RB, TPB, 0, stream>>>(x, n, W, out);
}

// Round 13
// 46.274 us; speedup vs baseline: 11.3747x; 1.3167x over previous
//
#include <hip/hip_runtime.h>
#include <stdint.h>

#define TPB 512         // threads per block (8 waves)
#define MMB 512         // minmax grid blocks / mm partial pairs
#define PB  256         // presel grid blocks (256*8 = 2048 waves -> same 1/16 sample)
#define RB  512         // rescore grid blocks
#define CHUNK 256       // elements per sampled chunk
#define NSAMP (PB * 8)  // sampled chunks (one per wave)

// d_ws float-index layout (~160 KB used):
#define OFF_CNT    0        // [0]=presel done-counter, [1]=rescore done-counter (u32)
#define OFF_MM     256      // 2*MMB minmax partials {min,max}
#define OFF_TOP    2304     // 8 * float4 top-8 params {inv_s, s, lo, hi}
#define OFF_TOPK   2336     // 8 u32 top-8 candidate ids
#define OFF_NMIN8  2352     // 8 new_min of top-8
#define OFF_NMAX8  2368     // 8 new_max of top-8
#define OFF_PSC    4096     // PB*128 presel partials, block-major [b][k]
#define OFF_RPART  36864    // RB*8 rescore partials

// exact reference fp32 order — identical everywhere params are derived
__device__ __forceinline__ float4 cand_params(int k, float xmin, float xmax,
                                              float* nmin_out, float* nmax_out) {
    float xrange = xmax - xmin;
    int ii = k >> 4;
    float zpf = (float)(k & 15);
    float tmp_max = xrange / 8.0f * (float)(ii + 1);
    float tmp_delta = tmp_max / 15.0f;
    float shift = zpf * tmp_delta;
    float new_min = fmaxf(0.0f - shift, xmin);
    float new_max = fminf(tmp_max - shift, xmax);
    float min_neg = fminf(new_min, 0.0f);
    float max_pos = fmaxf(new_max, 0.0f);
    float scale = fmaxf((max_pos - min_neg) / 15.0f, 1e-8f);
    float zp = 0.0f - rintf(min_neg / scale);
    zp = fminf(fmaxf(zp, 0.0f), 15.0f);
    float4 p;
    p.x = 1.0f / scale;
    p.y = scale;
    p.z = 0.0f - zp;
    p.w = 15.0f - zp;
    *nmin_out = new_min;
    *nmax_out = new_max;
    return p;
}

#define QUANT1(xv) { \
    float t0_ = (xv) * p0.x; float r0_ = rintf(t0_); \
    float c0_ = __builtin_amdgcn_fmed3f(r0_, p0.z, p0.w); \
    float d0_ = __builtin_fmaf(c0_, p0.y, -(xv)); \
    a0 = __builtin_fmaf(d0_, d0_, a0); \
    float t1_ = (xv) * p1.x; float r1_ = rintf(t1_); \
    float c1_ = __builtin_amdgcn_fmed3f(r1_, p1.z, p1.w); \
    float d1_ = __builtin_fmaf(c1_, p1.y, -(xv)); \
    a1 = __builtin_fmaf(d1_, d1_, a1); }
#define QUANT4(V) { QUANT1(V.x) QUANT1(V.y) QUANT1(V.z) QUANT1(V.w) }

#define RQc(xv, qc, acc) { \
    float t_ = (xv) * qc.x; float r_ = rintf(t_); \
    float c_ = __builtin_amdgcn_fmed3f(r_, qc.z, qc.w); \
    float d_ = __builtin_fmaf(c_, qc.y, -(xv)); \
    acc = __builtin_fmaf(d_, d_, acc); }
#define RQ8(xv) { RQc(xv,q0,b0) RQc(xv,q1,b1) RQc(xv,q2,b2) RQc(xv,q3,b3) \
                  RQc(xv,q4,b4) RQc(xv,q5,b5) RQc(xv,q6,b6) RQc(xv,q7,b7) }

// relaxed agent-scope atomics: coherence-point path, NO cache flush ops
#define ALOADF(p)    __hip_atomic_load((p), __ATOMIC_RELAXED, __HIP_MEMORY_SCOPE_AGENT)
#define ASTOREF(p,v) __hip_atomic_store((p), (v), __ATOMIC_RELAXED, __HIP_MEMORY_SCOPE_AGENT)

// ---- kernel 1: minmax block partials (+ zero the done-counters for this call) ----
__global__ __launch_bounds__(TPB) void k_minmax(const float* __restrict__ x, int n,
                                                float* __restrict__ W) {
    if (blockIdx.x == 0 && threadIdx.x < 2) {
        __hip_atomic_store(&((uint32_t*)W)[OFF_CNT + threadIdx.x], 0u,
                           __ATOMIC_RELAXED, __HIP_MEMORY_SCOPE_AGENT);
    }
    float* mm = W + OFF_MM;
    int n4 = n >> 2;
    const float4* x4 = (const float4*)x;
    float mn = INFINITY, mx = -INFINITY;
    int idx = blockIdx.x * TPB + threadIdx.x;
    int stride = gridDim.x * TPB;
    for (int i = idx; i < n4; i += stride) {
        float4 v = x4[i];
        mn = fminf(mn, fminf(fminf(v.x, v.y), fminf(v.z, v.w)));
        mx = fmaxf(mx, fmaxf(fmaxf(v.x, v.y), fmaxf(v.z, v.w)));
    }
    for (int i = (n4 << 2) + idx; i < n; i += stride) {
        float v = x[i];
        mn = fminf(mn, v);
        mx = fmaxf(mx, v);
    }
    #pragma unroll
    for (int m = 32; m; m >>= 1) {
        mn = fminf(mn, __shfl_xor(mn, m, 64));
        mx = fmaxf(mx, __shfl_xor(mx, m, 64));
    }
    __shared__ float smn[8], smx[8];
    int wv = threadIdx.x >> 6;
    if ((threadIdx.x & 63) == 0) { smn[wv] = mn; smx[wv] = mx; }
    __syncthreads();
    if (threadIdx.x == 0) {
        float a = smn[0], b = smx[0];
        #pragma unroll
        for (int w = 1; w < 8; ++w) { a = fminf(a, smn[w]); b = fmaxf(b, smx[w]); }
        mm[2 * blockIdx.x + 0] = a;
        mm[2 * blockIdx.x + 1] = b;
    }
}

// ---- kernel 2: presel sample-score; last-arriving block reduces + selects top-8 ----
__global__ __launch_bounds__(TPB) void k_presel(const float* __restrict__ x, int n,
                                                float* __restrict__ W, int nwc,
                                                int gstride) {
    __shared__ float ls[8][CHUNK];       // 8 KB staging, wave-private
    __shared__ float wsum[8][128];       // 4 KB
    __shared__ float smn[8], smx[8];
    __shared__ float sjs[128][4];
    __shared__ unsigned long long keys[128];
    __shared__ unsigned long long lmin[8];
    __shared__ int sel[8];
    __shared__ int lastFlag;
    int tid = threadIdx.x, lane = tid & 63;
    int wv = __builtin_amdgcn_readfirstlane(tid >> 6);
    const float* mm = W + OFF_MM;

    // exact global minmax (order-free fmin/fmax over partials)
    float mn = INFINITY, mx = -INFINITY;
    for (int e = tid; e < MMB; e += TPB) {
        mn = fminf(mn, mm[2 * e + 0]);
        mx = fmaxf(mx, mm[2 * e + 1]);
    }
    #pragma unroll
    for (int m = 32; m; m >>= 1) {
        mn = fminf(mn, __shfl_xor(mn, m, 64));
        mx = fmaxf(mx, __shfl_xor(mx, m, 64));
    }
    if (lane == 0) { smn[wv] = mn; smx[wv] = mx; }
    __syncthreads();
    float xmin = smn[0], xmax = smx[0];
    #pragma unroll
    for (int w = 1; w < 8; ++w) {
        xmin = fminf(xmin, smn[w]);
        xmax = fmaxf(xmax, smx[w]);
    }
    float dum0, dum1;
    float4 p0 = cand_params(2 * lane + 0, xmin, xmax, &dum0, &dum1);
    float4 p1 = cand_params(2 * lane + 1, xmin, xmax, &dum0, &dum1);
    float a0 = 0.0f, a1 = 0.0f;
    long nl = (long)n;

    // deterministic 1/16 chunk sample, one chunk per wave (same chunk SET as R12)
    long g = (long)(blockIdx.x * 8 + wv) * gstride;
    if (g < (long)nwc) {
        long base = g * CHUNK;
        long e = base + (long)lane * 4;
        float4 v;
        if (base + CHUNK <= nl) {
            v = *(const float4*)(x + e);
        } else {
            v.x = (e + 0 < nl) ? x[e + 0] : 0.0f;   // pad scores 0 for every cand
            v.y = (e + 1 < nl) ? x[e + 1] : 0.0f;
            v.z = (e + 2 < nl) ? x[e + 2] : 0.0f;
            v.w = (e + 3 < nl) ? x[e + 3] : 0.0f;
        }
        *(float4*)(&ls[wv][lane * 4]) = v;
        asm volatile("s_waitcnt lgkmcnt(0)" ::: "memory");  // wave-private region
        __builtin_amdgcn_sched_barrier(0);
        const float4* l4 = (const float4*)(&ls[wv][0]);
        #pragma unroll 4
        for (int i = 0; i < CHUNK / 4; ++i) {
            float4 u = l4[i];
            QUANT4(u)
        }
    }
    wsum[wv][2 * lane + 0] = a0;
    wsum[wv][2 * lane + 1] = a1;
    __syncthreads();
    if (tid < 128) {
        float s = ((wsum[0][tid] + wsum[1][tid]) + (wsum[2][tid] + wsum[3][tid]))
                + ((wsum[4][tid] + wsum[5][tid]) + (wsum[6][tid] + wsum[7][tid]));
        ASTOREF(&W[OFF_PSC + blockIdx.x * 128 + tid], s);   // agent-visible store
    }
    __syncthreads();   // drains vmcnt of the agent stores
    if (tid == 0) {
        uint32_t old = __hip_atomic_fetch_add(&((uint32_t*)W)[OFF_CNT + 0], 1u,
                                              __ATOMIC_RELAXED, __HIP_MEMORY_SCOPE_AGENT);
        lastFlag = (old == PB - 1);
    }
    __syncthreads();
    if (!lastFlag) return;

    // tail: 4-slice parallel fixed-order score reduce (depth 64), top-8 lex-min.
    {
        int k = tid & 127, j = tid >> 7;            // j = 0..3
        const float* p = W + OFF_PSC;
        float s = 0.0f;
        for (int b = j * (PB / 4); b < (j + 1) * (PB / 4); ++b)  // fixed order
            s += ALOADF(&p[b * 128 + k]);
        sjs[k][j] = s;
    }
    __syncthreads();
    if (tid < 128) {
        float sc = (sjs[tid][0] + sjs[tid][1]) + (sjs[tid][2] + sjs[tid][3]);
        uint32_t tb = __float_as_uint(sc);
        tb = (tb & 0x80000000u) ? ~tb : (tb | 0x80000000u);   // order-preserving
        keys[tid] = (((unsigned long long)tb) << 32) | (unsigned)tid;
    }
    __syncthreads();
    for (int r = 0; r < 8; ++r) {
        unsigned long long kk = (tid < 128) ? keys[tid] : ~0ull;
        #pragma unroll
        for (int m = 32; m; m >>= 1) {
            unsigned long long o = __shfl_xor(kk, m, 64);
            kk = (o < kk) ? o : kk;
        }
        if (lane == 0) lmin[wv] = kk;
        __syncthreads();
        if (tid == 0) {
            unsigned long long g2 = lmin[0];
            if (lmin[1] < g2) g2 = lmin[1];
            int kid = (int)(g2 & 0x7fu);
            sel[r] = kid;
            keys[kid] = ~0ull;
        }
        __syncthreads();
    }
    if (tid < 8) {
        int kid = sel[tid];
        float nmi, nma;
        float4 p = cand_params(kid, xmin, xmax, &nmi, &nma);
        ((float4*)(W + OFF_TOP))[tid] = p;                  // handoff via dispatch fence
        ((uint32_t*)(W + OFF_TOPK))[tid] = (uint32_t)kid;
        W[OFF_NMIN8 + tid] = nmi;
        W[OFF_NMAX8 + tid] = nma;
    }
}

// ---- kernel 3: exact rescore of 8 finalists; last block reduces + outputs ----
__global__ __launch_bounds__(TPB) void k_rescore(const float* __restrict__ x, int n,
                                                 float* __restrict__ W,
                                                 float* __restrict__ out) {
    __shared__ float ws2[8][8];
    __shared__ float red[8][64];
    __shared__ float Sc[8];
    __shared__ int lastFlag;
    const float4* P4v = (const float4*)(W + OFF_TOP);
    float4 q0 = P4v[0], q1 = P4v[1], q2 = P4v[2], q3 = P4v[3];
    float4 q4 = P4v[4], q5 = P4v[5], q6 = P4v[6], q7 = P4v[7];
    float b0 = 0, b1 = 0, b2 = 0, b3 = 0, b4 = 0, b5 = 0, b6 = 0, b7 = 0;
    int n4 = n >> 2;
    const float4* x4 = (const float4*)x;
    int tid = threadIdx.x;
    int gtid = blockIdx.x * TPB + tid;
    int stride = gridDim.x * TPB;
    for (int i = gtid; i < n4; i += stride) {
        float4 v = x4[i];
        RQ8(v.x) RQ8(v.y) RQ8(v.z) RQ8(v.w)
    }
    for (int i = (n4 << 2) + gtid; i < n; i += stride) {
        float xv = x[i];
        RQ8(xv)
    }
    #pragma unroll
    for (int m = 32; m; m >>= 1) {
        b0 += __shfl_xor(b0, m, 64); b1 += __shfl_xor(b1, m, 64);
        b2 += __shfl_xor(b2, m, 64); b3 += __shfl_xor(b3, m, 64);
        b4 += __shfl_xor(b4, m, 64); b5 += __shfl_xor(b5, m, 64);
        b6 += __shfl_xor(b6, m, 64); b7 += __shfl_xor(b7, m, 64);
    }
    int wv = tid >> 6, lane = tid & 63;
    if (lane == 0) {
        ws2[wv][0] = b0; ws2[wv][1] = b1; ws2[wv][2] = b2; ws2[wv][3] = b3;
        ws2[wv][4] = b4; ws2[wv][5] = b5; ws2[wv][6] = b6; ws2[wv][7] = b7;
    }
    __syncthreads();
    if (tid < 8) {
        float s = ((ws2[0][tid] + ws2[1][tid]) + (ws2[2][tid] + ws2[3][tid]))
                + ((ws2[4][tid] + ws2[5][tid]) + (ws2[6][tid] + ws2[7][tid]));
        ASTOREF(&W[OFF_RPART + blockIdx.x * 8 + tid], s);
    }
    __syncthreads();   // drains vmcnt of the agent stores
    if (tid == 0) {
        uint32_t old = __hip_atomic_fetch_add(&((uint32_t*)W)[OFF_CNT + 1], 1u,
                                              __ATOMIC_RELAXED, __HIP_MEMORY_SCOPE_AGENT);
        lastFlag = (old == RB - 1);
    }
    __syncthreads();
    if (!lastFlag) return;

    // tail: 64-slice fixed-order reduce (depth 8) + lex (S,k) argmin + output
    {
        int c = tid >> 6, j = tid & 63;
        float s = 0.0f;
        for (int b = j; b < RB; b += 64) s += ALOADF(&W[OFF_RPART + b * 8 + c]);
        red[c][j] = s;
    }
    __syncthreads();
    if ((tid & 63) == 0) {
        int c = tid >> 6;
        float t = 0.0f;
        for (int jj = 0; jj < 64; ++jj) t += red[c][jj];    // fixed order
        Sc[c] = t;
    }
    __syncthreads();
    if (tid == 0) {
        const uint32_t* KK = (const uint32_t*)(W + OFF_TOPK);
        float bs = Sc[0]; uint32_t bk = KK[0]; int br = 0;
        for (int cc = 1; cc < 8; ++cc) {
            uint32_t kc = KK[cc];
            if (Sc[cc] < bs || (Sc[cc] == bs && kc < bk)) { bs = Sc[cc]; bk = kc; br = cc; }
        }
        out[0] = W[OFF_NMIN8 + br];
        out[1] = W[OFF_NMAX8 + br];
    }
}

extern "C" void kernel_launch(void* const* d_in, const int* in_sizes, int n_in,
                              void* d_out, int out_size, void* d_ws, size_t ws_size,
                              hipStream_t stream) {
    const float* x = (const float*)d_in[0];
    int n = in_sizes[0];
    float* out = (float*)d_out;
    float* W = (float*)d_ws;

    int nwc = (n + CHUNK - 1) / CHUNK;
    int gstride = nwc / NSAMP;
    if (gstride < 1) gstride = 1;

    k_minmax<<<MMB, TPB, 0, stream>>>(x, n, W);
    k_presel<<<PB, TPB, 0, stream>>>(x, n, W, nwc, gstride);
    k_rescore<<<RB, TPB, 0, stream>>>(x, n, W, out);
}